// Round 6
// baseline (238.345 us; speedup 1.0000x reference)
//
#include <hip/hip_runtime.h>
#include <hip/hip_bf16.h>
#include <math.h>

#define MAXN    32
#define NPTS    16384
#define RSTRIDE 64              // ushorts per psi row (128 B): features 1..64 (rank-1 head via C-init)
#define BTA     16              // output rows per block
#define STRIPC  256             // cols per strip (1 KB fp32)
#define W0_OFF  (NPTS * RSTRIDE)

typedef __attribute__((ext_vector_type(8))) short         bf16x8;
typedef __attribute__((ext_vector_type(4))) float         f32x4;
typedef __attribute__((ext_vector_type(4))) unsigned int  u32x4;

__device__ inline ushort f2bf(float f) {
    union { float f; unsigned u; } v; v.f = f;
    unsigned u = v.u;
    u += 0x7FFFu + ((u >> 16) & 1u);   // round-to-nearest-even
    return (ushort)(u >> 16);
}

// ---------------- kernel 1: psi rows (bf16, chunk-swizzled) -----------------
// Row r = 8x16B chunks, chunk j stored at slot (j ^ (r&7)) — involution that
// bank-balances gram's 128B-row-stride b128 accesses. Rows routed through LDS
// so global stores are 1KB-contiguous per wave-instruction.
__global__ __launch_bounds__(256) void psi_kernel(
    const float* __restrict__ xs, const float* __restrict__ logits,
    ushort* __restrict__ psi, float* __restrict__ w0scr)
{
    __shared__ ushort srow[256 * RSTRIDE];   // 32 KB

    const int tid = threadIdx.x;
    const int pt  = blockIdx.x * 256 + tid;

    float x = xs[pt];
    x = fminf(1.0f, fmaxf(-1.0f, x));
    float s = sqrtf(fmaxf(0.0f, 1.0f - x * x));

    float m = -3.4e38f;
    #pragma unroll
    for (int n = 0; n <= MAXN; ++n) m = fmaxf(m, logits[n]);
    float sum = 0.0f;
    #pragma unroll
    for (int n = 0; n <= MAXN; ++n) sum += __expf(logits[n] - m);
    float inv = 1.0f / sum;

    if (pt == 0) w0scr[0] = __expf(logits[0] - m) * inv;   // w0, fp32-exact

    ushort tmp[RSTRIDE];
    float Tm1 = 1.0f, T = x;        // T_0, T_1
    float Um1 = 1.0f, U = 2.0f * x; // U_0, U_1
    float tx = 2.0f * x;
    #pragma unroll
    for (int n = 1; n <= MAXN; ++n) {
        float swn = sqrtf(__expf(logits[n] - m) * inv);
        tmp[2 * n - 2] = f2bf(swn * T);
        tmp[2 * n - 1] = f2bf(swn * (s * Um1));
        float Tn = tx * T - Tm1; Tm1 = T; T = Tn;
        float Un = tx * U - Um1; Um1 = U; U = Un;
    }

    {
        u32x4* lrow = (u32x4*)(srow + tid * RSTRIDE);
        const u32x4* src = (const u32x4*)tmp;
        const int rx = tid & 7;
        #pragma unroll
        for (int j = 0; j < 8; ++j) lrow[j ^ rx] = src[j];
    }
    __syncthreads();

    {
        const u32x4* ls = (const u32x4*)srow;
        u32x4* gd = (u32x4*)(psi + (size_t)blockIdx.x * 256 * RSTRIDE);
        #pragma unroll
        for (int i = 0; i < 8; ++i) gd[i * 256 + tid] = ls[i * 256 + tid];
    }
}

// ------- kernel 2: gram = w0 + psi @ psi^T, 16 rows x 16384 cols per block --
// Barrier-free: A in VGPRs (loaded once), B streamed from global (L2-resident),
// per-wave private LDS transpose buffer, 1KB-contiguous stores, zero
// __syncthreads. 8 independent waves/CU keep the store pipe continuously fed.
__global__ __launch_bounds__(256) void gram_kernel(
    const ushort* __restrict__ psi, const float* __restrict__ w0scr,
    float* __restrict__ out)
{
    __shared__ float buf[4 * BTA * STRIPC];   // 64 KB: 16 KB private per wave

    const int tid  = threadIdx.x;
    const int w    = tid >> 6;     // wave 0..3
    const int lane = tid & 63;
    const int lr   = lane & 15;    // D row within 16 / operand row index
    const int lh   = lane >> 4;    // k-chunk select / D col quad
    const int r7   = lr & 7;
    const int bi   = blockIdx.x;   // 0..1023: output rows bi*16..bi*16+15

    const float w0 = w0scr[0];

    // A fragments: psi row (bi*16+lr), chunk slots (ks*4+lh)^r7 — held in VGPRs
    const ushort* aRow = psi + (size_t)(bi * BTA + lr) * RSTRIDE;
    bf16x8 a0 = *(const bf16x8*)(aRow + ((lh ^ r7) * 8));
    bf16x8 a1 = *(const bf16x8*)(aRow + (((4 + lh) ^ r7) * 8));

    float* mybuf = buf + w * BTA * STRIPC;
    const int rxw = r7 << 2;           // transpose-write XOR (dwords)

    for (int s = 0; s < 16; ++s) {
        const int colbase = (s * 4 + w) * STRIPC;   // waves interleave strips

        f32x4 acc[16];
        #pragma unroll
        for (int ct = 0; ct < 16; ++ct) acc[ct] = (f32x4){w0, w0, w0, w0};

        const ushort* bBase = psi + (size_t)colbase * RSTRIDE;
        #pragma unroll
        for (int ct = 0; ct < 16; ++ct) {
            const ushort* bRow = bBase + (ct * 16 + lr) * RSTRIDE;
            bf16x8 b0 = *(const bf16x8*)(bRow + ((lh ^ r7) * 8));
            bf16x8 b1 = *(const bf16x8*)(bRow + (((4 + lh) ^ r7) * 8));
            // swapped operands: D row = lr, D col = lh*4 + reg (+ ct*16)
            acc[ct] = __builtin_amdgcn_mfma_f32_16x16x32_bf16(b0, a0, acc[ct], 0, 0, 0);
            acc[ct] = __builtin_amdgcn_mfma_f32_16x16x32_bf16(b1, a1, acc[ct], 0, 0, 0);
        }

        // transpose through private LDS (in-wave ordering via lgkmcnt; no barrier)
        #pragma unroll
        for (int ct = 0; ct < 16; ++ct) {
            int col = (lh * 4 + ct * 16) ^ rxw;
            *(f32x4*)(mybuf + lr * STRIPC + col) = acc[ct];
        }

        // stream out: 16 instrs, each 1 row x 1024 B contiguous
        #pragma unroll
        for (int r = 0; r < 16; ++r) {
            int colr = (lane * 4) ^ ((r & 7) << 2);
            f32x4 v = *(const f32x4*)(mybuf + r * STRIPC + colr);
            float* dst = out + (size_t)(bi * BTA + r) * NPTS + colbase + lane * 4;
            *(f32x4*)dst = v;
        }
    }
}

extern "C" void kernel_launch(void* const* d_in, const int* in_sizes, int n_in,
                              void* d_out, int out_size, void* d_ws, size_t ws_size,
                              hipStream_t stream) {
    const float* xs     = (const float*)d_in[0];
    const float* logits = (const float*)d_in[1];
    float* out          = (float*)d_out;
    ushort* psi         = (ushort*)d_ws;                  // NPTS*64*2 = 2 MB
    float*  w0scr       = (float*)((char*)d_ws + (size_t)W0_OFF * 2);

    psi_kernel<<<NPTS / 256, 256, 0, stream>>>(xs, logits, psi, w0scr);

    gram_kernel<<<NPTS / BTA, 256, 0, stream>>>(psi, w0scr, out);
}

// Round 7
// 182.298 us; speedup vs baseline: 1.3074x; 1.3074x over previous
//
#include <hip/hip_runtime.h>
#include <hip/hip_bf16.h>
#include <math.h>

#define MAXN    32
#define NPTS    16384
#define RSTRIDE 64              // ushorts per psi row (128 B): features 1..64 (rank-1 head via C-init)
#define BTA     32              // output tile rows per block
#define BTB     256             // output tile cols per block
#define NCHUNK  ((BTA + BTB) * RSTRIDE * 2 / 1024)   // 36 x 1KiB staging chunks
#define W0_OFF  (NPTS * RSTRIDE)

typedef __attribute__((ext_vector_type(8))) short         bf16x8;
typedef __attribute__((ext_vector_type(4))) float         f32x4;
typedef __attribute__((ext_vector_type(4))) unsigned int  u32x4;

__device__ inline ushort f2bf(float f) {
    union { float f; unsigned u; } v; v.f = f;
    unsigned u = v.u;
    u += 0x7FFFu + ((u >> 16) & 1u);   // round-to-nearest-even
    return (ushort)(u >> 16);
}

// ---------------- kernel 1: psi rows (bf16, chunk-swizzled) -----------------
// Row r = 8x16B chunks, chunk j stored at slot (j ^ (r&7)) — involution that
// bank-balances gram's 128B-row-stride b128 reads. Rows routed through LDS so
// global stores are 1KB-contiguous per wave-instruction.
__global__ __launch_bounds__(256) void psi_kernel(
    const float* __restrict__ xs, const float* __restrict__ logits,
    ushort* __restrict__ psi, float* __restrict__ w0scr)
{
    __shared__ ushort srow[256 * RSTRIDE];   // 32 KB

    const int tid = threadIdx.x;
    const int pt  = blockIdx.x * 256 + tid;

    float x = xs[pt];
    x = fminf(1.0f, fmaxf(-1.0f, x));
    float s = sqrtf(fmaxf(0.0f, 1.0f - x * x));

    float m = -3.4e38f;
    #pragma unroll
    for (int n = 0; n <= MAXN; ++n) m = fmaxf(m, logits[n]);
    float sum = 0.0f;
    #pragma unroll
    for (int n = 0; n <= MAXN; ++n) sum += __expf(logits[n] - m);
    float inv = 1.0f / sum;

    if (pt == 0) w0scr[0] = __expf(logits[0] - m) * inv;   // w0, fp32-exact

    ushort tmp[RSTRIDE];
    float Tm1 = 1.0f, T = x;        // T_0, T_1
    float Um1 = 1.0f, U = 2.0f * x; // U_0, U_1
    float tx = 2.0f * x;
    #pragma unroll
    for (int n = 1; n <= MAXN; ++n) {
        float swn = sqrtf(__expf(logits[n] - m) * inv);
        tmp[2 * n - 2] = f2bf(swn * T);
        tmp[2 * n - 1] = f2bf(swn * (s * Um1));
        float Tn = tx * T - Tm1; Tm1 = T; T = Tn;
        float Un = tx * U - Um1; Um1 = U; U = Un;
    }

    {
        u32x4* lrow = (u32x4*)(srow + tid * RSTRIDE);
        const u32x4* src = (const u32x4*)tmp;
        const int rx = tid & 7;
        #pragma unroll
        for (int j = 0; j < 8; ++j) lrow[j ^ rx] = src[j];
    }
    __syncthreads();

    {
        const u32x4* ls = (const u32x4*)srow;
        u32x4* gd = (u32x4*)(psi + (size_t)blockIdx.x * 256 * RSTRIDE);
        #pragma unroll
        for (int i = 0; i < 8; ++i) gd[i * 256 + tid] = ls[i * 256 + tid];
    }
}

// ---------------- kernel 2: gram = w0 + psi @ psi^T, 32x256 tile ------------
__device__ inline void load_lds16(const void* g, void* l) {
    __builtin_amdgcn_global_load_lds(
        (const __attribute__((address_space(1))) unsigned*)g,
        (__attribute__((address_space(3))) unsigned*)l, 16, 0, 0);
}

__global__ __launch_bounds__(256, 4) void gram_kernel(
    const ushort* __restrict__ psi, const float* __restrict__ w0scr,
    float* __restrict__ out)
{
    // staging: bytes [0,4096) = A panel (32 rows x 128B),
    //          bytes [4096,36864) = B panel (256 rows x 128B)
    // after compute: bytes [0,32768) reused as fp32 [32][256] tile
    __shared__ float ldsF[NCHUNK * 256];   // 36864 B -> 4 blocks/CU

    const int tid  = threadIdx.x;
    const int w    = tid >> 6;     // wave 0..3: owns output col-slab w*64..w*64+63
    const int lane = tid & 63;
    const int lr   = lane & 15;    // operand row index within 16-tile / D row
    const int lh   = lane >> 4;    // k-chunk select / D col quad
    const int r7   = lr & 7;
    const int bi   = blockIdx.y;   // 0..511 (row tile)
    const int bj   = blockIdx.x;   // 0..63  (col tile)

    const float w0 = w0scr[0];

    // ---- stage 36 x 1KiB chunks (A: 4, B: 32), linear LDS dest ----
    {
        const char* gA = (const char*)(psi + (size_t)bi * BTA * RSTRIDE);
        const char* gB = (const char*)(psi + (size_t)bj * BTB * RSTRIDE);
        char* lbase = (char*)ldsF;
        for (int q = w; q < NCHUNK; q += 4) {
            const char* src = (q < 4) ? (gA + q * 1024) : (gB + (q - 4) * 1024);
            load_lds16(src + lane * 16, lbase + q * 1024);
        }
    }
    __syncthreads();

    const char* aPanel = (const char*)ldsF;
    const char* bPanel = (const char*)ldsF + 4096;

    f32x4 acc[2][4];
    #pragma unroll
    for (int rt = 0; rt < 2; ++rt)
        #pragma unroll
        for (int ct = 0; ct < 4; ++ct) acc[rt][ct] = (f32x4){w0, w0, w0, w0};

    #pragma unroll
    for (int ks = 0; ks < 2; ++ks) {
        const int sx = ((ks * 4 + lh) ^ r7) * 16;
        bf16x8 a0 = *(const bf16x8*)(aPanel + (lr      ) * 128 + sx);
        bf16x8 a1 = *(const bf16x8*)(aPanel + (16 + lr ) * 128 + sx);
        #pragma unroll
        for (int ct = 0; ct < 4; ++ct) {
            bf16x8 b = *(const bf16x8*)(bPanel + (w * 64 + ct * 16 + lr) * 128 + sx);
            // swapped operands: D row = lr (+rt*16), D col = lh*4 + reg (+ w*64 + ct*16)
            acc[0][ct] = __builtin_amdgcn_mfma_f32_16x16x32_bf16(b, a0, acc[0][ct], 0, 0, 0);
            acc[1][ct] = __builtin_amdgcn_mfma_f32_16x16x32_bf16(b, a1, acc[1][ct], 0, 0, 0);
        }
    }

    // ---- epilogue: transpose through LDS for 1KB-contiguous stores ----
    __syncthreads();   // all waves done reading staged psi
    {
        #pragma unroll
        for (int rt = 0; rt < 2; ++rt) {
            const int row = rt * 16 + lr;
            const int rxe = (row & 7) << 2;
            #pragma unroll
            for (int ct = 0; ct < 4; ++ct) {
                int col = (w * 64 + ct * 16 + lh * 4) ^ rxe;
                *(f32x4*)(ldsF + row * BTB + col) = acc[rt][ct];
            }
        }
    }
    __syncthreads();

    // ---- stream out: 8 passes, per-wave-instruction = 1 row x 1024 B ----
    {
        #pragma unroll
        for (int p = 0; p < 8; ++p) {
            int row  = p * 4 + w;
            int colr = (lane * 4) ^ ((row & 7) << 2);
            f32x4 v = *(const f32x4*)(ldsF + row * BTB + colr);
            float* dst = out + (size_t)(bi * BTA + row) * NPTS + (size_t)bj * BTB + lane * 4;
            *(f32x4*)dst = v;
        }
    }
}

extern "C" void kernel_launch(void* const* d_in, const int* in_sizes, int n_in,
                              void* d_out, int out_size, void* d_ws, size_t ws_size,
                              hipStream_t stream) {
    const float* xs     = (const float*)d_in[0];
    const float* logits = (const float*)d_in[1];
    float* out          = (float*)d_out;
    ushort* psi         = (ushort*)d_ws;                  // NPTS*64*2 = 2 MB
    float*  w0scr       = (float*)((char*)d_ws + (size_t)W0_OFF * 2);

    psi_kernel<<<NPTS / 256, 256, 0, stream>>>(xs, logits, psi, w0scr);

    dim3 grid(NPTS / BTB, NPTS / BTA);
    gram_kernel<<<grid, 256, 0, stream>>>(psi, w0scr, out);
}